// Round 2
// baseline (968.926 us; speedup 1.0000x reference)
//
#include <hip/hip_runtime.h>
#include <hip/hip_bf16.h>
#include <stdint.h>

typedef __bf16 bf16_t;
typedef bf16_t bf16x8 __attribute__((ext_vector_type(8)));
typedef bf16_t bf16x4 __attribute__((ext_vector_type(4)));
typedef float f32x4 __attribute__((ext_vector_type(4)));

#define MFMA16(acc, a, b) __builtin_amdgcn_mfma_f32_16x16x32_bf16((a), (b), (acc), 0, 0, 0)

#define NN 16384
#define XC 5000
#define HD 768

// ---------------- prep: dst[c][kp] = (kp<K) ? src[kp][c] : 0  (bf16, zero-padded K)
__global__ void k_transpose_pad(const float* __restrict__ src, bf16_t* __restrict__ dst,
                                int K, int C, int Kpad) {
  int idx = blockIdx.x * 256 + threadIdx.x;
  if (idx >= C * Kpad) return;
  int c = idx / Kpad, kp = idx - c * Kpad;
  float v = (kp < K) ? src[(size_t)kp * C + c] : 0.0f;
  dst[idx] = (bf16_t)v;
}

// ---------------- stage 1: h[:, br*256+c] = relu(x_slice @ Wbr + bbr)   (bf16 out)
// 256 thr, BM=64, BN=256, BK=32; 4 waves each 64x64
__global__ __launch_bounds__(256, 2)
void k_branch_mlp(const float* __restrict__ x,
                  const bf16_t* __restrict__ W1T, const bf16_t* __restrict__ W2T,
                  const bf16_t* __restrict__ W3T,
                  const float* __restrict__ b1, const float* __restrict__ b2,
                  const float* __restrict__ b3,
                  bf16_t* __restrict__ h) {
  __shared__ __align__(16) bf16_t As[64 * 48];
  __shared__ __align__(16) bf16_t Bs[256 * 48];

  const int tid = threadIdx.x;
  const int lane = tid & 63, w = tid >> 6;
  const int ln = lane & 15, g = lane >> 4;
  const int row0 = blockIdx.x * 64;
  const int br = blockIdx.y;

  int Klim, Kpad, Foff;
  const bf16_t* BT; const float* bias;
  if (br == 0)      { Klim = 2000; Kpad = 2048; Foff = 0;    BT = W1T; bias = b1; }
  else if (br == 1) { Klim = 2000; Kpad = 2048; Foff = 2000; BT = W2T; bias = b2; }
  else              { Klim = 1000; Kpad = 1024; Foff = 4000; BT = W3T; bias = b3; }

  const int ar = tid >> 2, akq = tid & 3;  // A row 0..63, 8-f32 quarter
  const float* aptr = x + (size_t)(row0 + ar) * XC + Foff;
  const bf16_t* bptr = BT + (size_t)tid * Kpad;

  f32x4 zz = {0.f, 0.f, 0.f, 0.f};
  f32x4 acc[4][4];
#pragma unroll
  for (int m = 0; m < 4; ++m)
#pragma unroll
    for (int n = 0; n < 4; ++n) acc[m][n] = zz;

  float areg[8];
  bf16x8 breg[4];
  auto fetch = [&](int k0) {
    int kk = k0 + akq * 8;
    if (kk + 8 <= Klim) {
      float4 v0 = *(const float4*)(aptr + kk);
      float4 v1 = *(const float4*)(aptr + kk + 4);
      areg[0]=v0.x; areg[1]=v0.y; areg[2]=v0.z; areg[3]=v0.w;
      areg[4]=v1.x; areg[5]=v1.y; areg[6]=v1.z; areg[7]=v1.w;
    } else {
#pragma unroll
      for (int j = 0; j < 8; ++j) areg[j] = (kk + j < Klim) ? aptr[kk + j] : 0.0f;
    }
#pragma unroll
    for (int q = 0; q < 4; ++q) breg[q] = *(const bf16x8*)(bptr + k0 + q * 8);
  };

  fetch(0);
  for (int k0 = 0; k0 < Kpad; k0 += 32) {
    __syncthreads();
    bf16x8 av;
#pragma unroll
    for (int j = 0; j < 8; ++j) av[j] = (bf16_t)areg[j];
    *(bf16x8*)&As[ar * 48 + akq * 8] = av;
#pragma unroll
    for (int q = 0; q < 4; ++q) *(bf16x8*)&Bs[tid * 48 + q * 8] = breg[q];
    __syncthreads();
    if (k0 + 32 < Kpad) fetch(k0 + 32);
    bf16x8 af[4], bfr[4];
#pragma unroll
    for (int m = 0; m < 4; ++m) af[m] = *(const bf16x8*)&As[(16 * m + ln) * 48 + 8 * g];
#pragma unroll
    for (int n = 0; n < 4; ++n) bfr[n] = *(const bf16x8*)&Bs[(64 * w + 16 * n + ln) * 48 + 8 * g];
#pragma unroll
    for (int m = 0; m < 4; ++m)
#pragma unroll
      for (int n = 0; n < 4; ++n)
        acc[m][n] = MFMA16(acc[m][n], af[m], bfr[n]);
  }

  // epilogue: bias + relu -> h (row-major bf16). D frag: col=ln, row=4g+i.
#pragma unroll
  for (int n = 0; n < 4; ++n) {
    int cl = 64 * w + 16 * n + ln;
    float bv = bias[cl];
    int hcol = br * 256 + cl;
#pragma unroll
    for (int m = 0; m < 4; ++m)
#pragma unroll
      for (int i = 0; i < 4; ++i) {
        int rr = row0 + 16 * m + 4 * g + i;
        float v = acc[m][n][i] + bv;
        h[(size_t)rr * HD + hcol] = (bf16_t)(v > 0.f ? v : 0.f);
      }
  }
}

// ---------------- stage 2: t1 = h @ gw1; writes t1T[c][row] (bf16, transposed)
__global__ __launch_bounds__(256, 2)
void k_t1(const bf16_t* __restrict__ h, const bf16_t* __restrict__ gw1T,
          bf16_t* __restrict__ t1T) {
  __shared__ __align__(16) bf16_t As[64 * 48];
  __shared__ __align__(16) bf16_t Bs[256 * 48];
  const int tid = threadIdx.x;
  const int lane = tid & 63, w = tid >> 6;
  const int ln = lane & 15, g = lane >> 4;
  const int row0 = blockIdx.x * 64;
  const int ar = tid >> 2, akq = tid & 3;
  const bf16_t* aptr = h + (size_t)(row0 + ar) * HD;
  const bf16_t* bptr = gw1T + (size_t)tid * HD;

  f32x4 zz = {0.f, 0.f, 0.f, 0.f};
  f32x4 acc[4][4];
#pragma unroll
  for (int m = 0; m < 4; ++m)
#pragma unroll
    for (int n = 0; n < 4; ++n) acc[m][n] = zz;

  bf16x8 areg; bf16x8 breg[4];
  auto fetch = [&](int k0) {
    areg = *(const bf16x8*)(aptr + k0 + akq * 8);
#pragma unroll
    for (int q = 0; q < 4; ++q) breg[q] = *(const bf16x8*)(bptr + k0 + q * 8);
  };
  fetch(0);
  for (int k0 = 0; k0 < HD; k0 += 32) {
    __syncthreads();
    *(bf16x8*)&As[ar * 48 + akq * 8] = areg;
#pragma unroll
    for (int q = 0; q < 4; ++q) *(bf16x8*)&Bs[tid * 48 + q * 8] = breg[q];
    __syncthreads();
    if (k0 + 32 < HD) fetch(k0 + 32);
    bf16x8 af[4], bfr[4];
#pragma unroll
    for (int m = 0; m < 4; ++m) af[m] = *(const bf16x8*)&As[(16 * m + ln) * 48 + 8 * g];
#pragma unroll
    for (int n = 0; n < 4; ++n) bfr[n] = *(const bf16x8*)&Bs[(64 * w + 16 * n + ln) * 48 + 8 * g];
#pragma unroll
    for (int m = 0; m < 4; ++m)
#pragma unroll
      for (int n = 0; n < 4; ++n)
        acc[m][n] = MFMA16(acc[m][n], af[m], bfr[n]);
  }

  // epilogue: t1T[c][row0+16m+4g+i], 4 consecutive rows -> packed 8B store
#pragma unroll
  for (int n = 0; n < 4; ++n) {
    int c = 64 * w + 16 * n + ln;
#pragma unroll
    for (int m = 0; m < 4; ++m) {
      bf16x4 p;
#pragma unroll
      for (int i = 0; i < 4; ++i) p[i] = (bf16_t)acc[m][n][i];
      *(bf16x4*)(t1T + (size_t)c * NN + row0 + 16 * m + 4 * g) = p;
    }
  }
}

// ---------------- stage 3: g1 = relu(adj@t1 + gb1); t2 = g1@gw2 (in-LDS); writes t2T
// 512 thr (8 waves), BM=64, BN=256, BK=32; wave w: cols 32w..32w+31
__global__ __launch_bounds__(512, 2)
void k_gcn1(const float* __restrict__ adj, const bf16_t* __restrict__ t1T,
            const float* __restrict__ gb1, const bf16_t* __restrict__ gw2T,
            bf16_t* __restrict__ t2T) {
  __shared__ __align__(16) char smem[50688];
  bf16_t* As  = (bf16_t*)smem;            // [64][48]   6144 B
  bf16_t* Bs  = (bf16_t*)(smem + 6144);   // [256][48] 24576 B
  bf16_t* g1s = (bf16_t*)smem;            // [64][264] 33792 B (union, post-loop)
  bf16_t* w2s = (bf16_t*)(smem + 33792);  // [32][264] 16896 B

  const int tid = threadIdx.x;
  const int lane = tid & 63, w = tid >> 6;      // w: 0..7
  const int ln = lane & 15, g = lane >> 4;
  const int row0 = blockIdx.x * 64;

  const int ar = tid >> 3, akq = tid & 7;       // A: row 0..63, 4-f32 chunk 0..7
  const int bc = tid >> 1, bh = tid & 1;        // B: col 0..255, 16-bf16 half
  const float*  aptr = adj + (size_t)(row0 + ar) * NN + akq * 4;
  const bf16_t* bptr = t1T + (size_t)bc * NN + bh * 16;

  // gw2T -> LDS (stays resident); simple scalar copy, runs once
  for (int i = tid; i < 32 * 256; i += 512) {
    int rr = i >> 8, s = i & 255;
    w2s[rr * 264 + s] = gw2T[i];
  }

  f32x4 zz = {0.f, 0.f, 0.f, 0.f};
  f32x4 acc[4][2];
#pragma unroll
  for (int m = 0; m < 4; ++m) { acc[m][0] = zz; acc[m][1] = zz; }

  float4 areg; bf16x8 breg[2];
  auto fetch = [&](int k0) {
    areg = *(const float4*)(aptr + k0);
    breg[0] = *(const bf16x8*)(bptr + k0);
    breg[1] = *(const bf16x8*)(bptr + k0 + 8);
  };
  fetch(0);
  for (int k0 = 0; k0 < NN; k0 += 32) {
    __syncthreads();
    bf16x4 av;
    av[0] = (bf16_t)areg.x; av[1] = (bf16_t)areg.y;
    av[2] = (bf16_t)areg.z; av[3] = (bf16_t)areg.w;
    *(bf16x4*)&As[ar * 48 + akq * 4] = av;
    *(bf16x8*)&Bs[bc * 48 + bh * 16] = breg[0];
    *(bf16x8*)&Bs[bc * 48 + bh * 16 + 8] = breg[1];
    __syncthreads();
    if (k0 + 32 < NN) fetch(k0 + 32);
    bf16x8 af[4], bfr[2];
#pragma unroll
    for (int m = 0; m < 4; ++m) af[m] = *(const bf16x8*)&As[(16 * m + ln) * 48 + 8 * g];
#pragma unroll
    for (int n = 0; n < 2; ++n) bfr[n] = *(const bf16x8*)&Bs[(32 * w + 16 * n + ln) * 48 + 8 * g];
#pragma unroll
    for (int m = 0; m < 4; ++m)
#pragma unroll
      for (int n = 0; n < 2; ++n)
        acc[m][n] = MFMA16(acc[m][n], af[m], bfr[n]);
  }

  // epilogue: g1 = relu(acc+gb1) -> LDS (bf16), then t2 = g1 @ gw2 via MFMA, write t2T
  __syncthreads();
#pragma unroll
  for (int n = 0; n < 2; ++n) {
    int cl = 32 * w + 16 * n + ln;
    float bv = gb1[cl];
#pragma unroll
    for (int m = 0; m < 4; ++m)
#pragma unroll
      for (int i = 0; i < 4; ++i) {
        float v = acc[m][n][i] + bv;
        g1s[(16 * m + 4 * g + i) * 264 + cl] = (bf16_t)(v > 0.f ? v : 0.f);
      }
  }
  __syncthreads();
  {
    int rw = w & 3, cn = w >> 2;   // 8 waves cover 4 row-groups x 2 col-frags
    f32x4 macc = zz;
#pragma unroll
    for (int ks = 0; ks < 8; ++ks) {
      bf16x8 ag = *(const bf16x8*)&g1s[(16 * rw + ln) * 264 + ks * 32 + 8 * g];
      bf16x8 bg = *(const bf16x8*)&w2s[(16 * cn + ln) * 264 + ks * 32 + 8 * g];
      macc = MFMA16(macc, ag, bg);
    }
    int c2 = 16 * cn + ln;
    bf16x4 p;
#pragma unroll
    for (int i = 0; i < 4; ++i) p[i] = (bf16_t)macc[i];
    *(bf16x4*)(t2T + (size_t)c2 * NN + row0 + 16 * rw + 4 * g) = p;
  }
}

// ---------------- stage 4: out = log_softmax(adj @ t2 + gb2)
// 256 thr, BM=32, per-wave split-K (4 x 4096), wave-private double-buffered LDS
__global__ __launch_bounds__(256, 2)
void k_gcn2(const float* __restrict__ adj, const bf16_t* __restrict__ t2T,
            const float* __restrict__ gb2, float* __restrict__ out) {
  __shared__ __align__(16) char smem[49152];
  float* Lg = (float*)smem;  // [4][32][32] f32, union (post-loop)
  const int tid = threadIdx.x;
  const int lane = tid & 63, w = tid >> 6;
  const int ln = lane & 15, g = lane >> 4;
  const int row0 = blockIdx.x * 32;

  bf16_t* A0 = (bf16_t*)(smem + w * 12288);
  bf16_t* B0 = (bf16_t*)(smem + w * 12288 + 3072);
  bf16_t* A1 = (bf16_t*)(smem + w * 12288 + 6144);
  bf16_t* B1 = (bf16_t*)(smem + w * 12288 + 9216);

  const int ar = lane >> 1, akq = lane & 1;  // row/col 0..31, 16-elem half
  const float*  aptr = adj + (size_t)(row0 + ar) * NN + akq * 16;
  const bf16_t* bptr = t2T + (size_t)ar * NN + akq * 16;

  f32x4 zz = {0.f, 0.f, 0.f, 0.f};
  f32x4 macc[2][2];
#pragma unroll
  for (int m = 0; m < 2; ++m) { macc[m][0] = zz; macc[m][1] = zz; }

  float areg[16]; bf16x8 breg[2];
  auto fetch = [&](int kb) {
#pragma unroll
    for (int q = 0; q < 4; ++q) {
      float4 v = *(const float4*)(aptr + kb + q * 4);
      areg[q*4+0]=v.x; areg[q*4+1]=v.y; areg[q*4+2]=v.z; areg[q*4+3]=v.w;
    }
    breg[0] = *(const bf16x8*)(bptr + kb);
    breg[1] = *(const bf16x8*)(bptr + kb + 8);
  };
  const int kb0 = w * 4096;
  fetch(kb0);
  for (int s = 0; s < 128; ++s) {
    bf16_t* Ab = (s & 1) ? A1 : A0;
    bf16_t* Bb = (s & 1) ? B1 : B0;
    bf16x8 av0, av1;
#pragma unroll
    for (int j = 0; j < 8; ++j) { av0[j] = (bf16_t)areg[j]; av1[j] = (bf16_t)areg[8 + j]; }
    *(bf16x8*)&Ab[ar * 48 + akq * 16] = av0;
    *(bf16x8*)&Ab[ar * 48 + akq * 16 + 8] = av1;
    *(bf16x8*)&Bb[ar * 48 + akq * 16] = breg[0];
    *(bf16x8*)&Bb[ar * 48 + akq * 16 + 8] = breg[1];
    if (s + 1 < 128) fetch(kb0 + (s + 1) * 32);
    bf16x8 af[2], bfr[2];
#pragma unroll
    for (int m = 0; m < 2; ++m) af[m] = *(const bf16x8*)&Ab[(16 * m + ln) * 48 + 8 * g];
#pragma unroll
    for (int n = 0; n < 2; ++n) bfr[n] = *(const bf16x8*)&Bb[(16 * n + ln) * 48 + 8 * g];
#pragma unroll
    for (int m = 0; m < 2; ++m)
#pragma unroll
      for (int n = 0; n < 2; ++n)
        macc[m][n] = MFMA16(macc[m][n], af[m], bfr[n]);
  }

  __syncthreads();
#pragma unroll
  for (int m = 0; m < 2; ++m)
#pragma unroll
    for (int n = 0; n < 2; ++n)
#pragma unroll
      for (int i = 0; i < 4; ++i) {
        int rl = 16 * m + 4 * g + i;
        int cl = 16 * n + ln;
        Lg[(w * 32 + rl) * 32 + cl] = macc[m][n][i];
      }
  __syncthreads();

  // reduce 4 K-partials + bias, then log_softmax per row (8 threads/row)
  int rr = tid >> 3, cg = tid & 7;
  float l4[4];
#pragma unroll
  for (int j = 0; j < 4; ++j) {
    int c = cg * 4 + j;
    l4[j] = Lg[rr * 32 + c] + Lg[(32 + rr) * 32 + c] +
            Lg[(64 + rr) * 32 + c] + Lg[(96 + rr) * 32 + c] + gb2[c];
  }
  float mx = fmaxf(fmaxf(l4[0], l4[1]), fmaxf(l4[2], l4[3]));
  mx = fmaxf(mx, __shfl_xor(mx, 1));
  mx = fmaxf(mx, __shfl_xor(mx, 2));
  mx = fmaxf(mx, __shfl_xor(mx, 4));
  float se = 0.f;
#pragma unroll
  for (int j = 0; j < 4; ++j) se += expf(l4[j] - mx);
  se += __shfl_xor(se, 1);
  se += __shfl_xor(se, 2);
  se += __shfl_xor(se, 4);
  float lse = mx + logf(se);
  float4 o;
  o.x = l4[0] - lse; o.y = l4[1] - lse; o.z = l4[2] - lse; o.w = l4[3] - lse;
  *(float4*)&out[(size_t)(row0 + rr) * 32 + cg * 4] = o;
}

extern "C" void kernel_launch(void* const* d_in, const int* in_sizes, int n_in,
                              void* d_out, int out_size, void* d_ws, size_t ws_size,
                              hipStream_t stream) {
  const float* x   = (const float*)d_in[0];
  const float* adj = (const float*)d_in[1];
  const float* W1  = (const float*)d_in[2];
  const float* b1  = (const float*)d_in[3];
  const float* W2  = (const float*)d_in[4];
  const float* b2  = (const float*)d_in[5];
  const float* W3  = (const float*)d_in[6];
  const float* b3  = (const float*)d_in[7];
  const float* gw1 = (const float*)d_in[8];
  const float* gb1 = (const float*)d_in[9];
  const float* gw2 = (const float*)d_in[10];
  const float* gb2 = (const float*)d_in[11];
  float* out = (float*)d_out;

  char* ws = (char*)d_ws;
  size_t off = 0;
  auto alloc = [&](size_t bytes) { char* p = ws + off; off += (bytes + 255) & ~(size_t)255; return p; };
  bf16_t* W1T  = (bf16_t*)alloc((size_t)256 * 2048 * 2);
  bf16_t* W2T  = (bf16_t*)alloc((size_t)256 * 2048 * 2);
  bf16_t* W3T  = (bf16_t*)alloc((size_t)256 * 1024 * 2);
  bf16_t* gw1T = (bf16_t*)alloc((size_t)256 * 768 * 2);
  bf16_t* gw2T = (bf16_t*)alloc((size_t)32 * 256 * 2);
  bf16_t* h    = (bf16_t*)alloc((size_t)NN * HD * 2);
  bf16_t* t1T  = (bf16_t*)alloc((size_t)256 * NN * 2);
  bf16_t* t2T  = (bf16_t*)alloc((size_t)32 * NN * 2);
  if (ws_size < off) return;  // workspace too small: bail (bench will show absmax fail)

  k_transpose_pad<<<(256 * 2048 + 255) / 256, 256, 0, stream>>>(W1, W1T, 2000, 256, 2048);
  k_transpose_pad<<<(256 * 2048 + 255) / 256, 256, 0, stream>>>(W2, W2T, 2000, 256, 2048);
  k_transpose_pad<<<(256 * 1024 + 255) / 256, 256, 0, stream>>>(W3, W3T, 1000, 256, 1024);
  k_transpose_pad<<<(256 * 768  + 255) / 256, 256, 0, stream>>>(gw1, gw1T, 768, 256, 768);
  k_transpose_pad<<<(32 * 256   + 255) / 256, 256, 0, stream>>>(gw2, gw2T, 256, 32, 256);

  k_branch_mlp<<<dim3(256, 3), 256, 0, stream>>>(x, W1T, W2T, W3T, b1, b2, b3, h);
  k_t1<<<256, 256, 0, stream>>>(h, gw1T, t1T);
  k_gcn1<<<256, 512, 0, stream>>>(adj, t1T, gb1, gw2T, t2T);
  k_gcn2<<<512, 256, 0, stream>>>(adj, t2T, gb2, out);
}

// Round 3
// 757.948 us; speedup vs baseline: 1.2784x; 1.2784x over previous
//
#include <hip/hip_runtime.h>
#include <hip/hip_bf16.h>
#include <stdint.h>

typedef __bf16 bf16_t;
typedef bf16_t bf16x8 __attribute__((ext_vector_type(8)));
typedef bf16_t bf16x4 __attribute__((ext_vector_type(4)));
typedef float f32x4 __attribute__((ext_vector_type(4)));

#define MFMA16(acc, a, b) __builtin_amdgcn_mfma_f32_16x16x32_bf16((a), (b), (acc), 0, 0, 0)

#define NN 16384
#define XC 5000
#define HD 768

// ---------------- prep: dst[c][kp] = (kp<K) ? src[kp][c] : 0  (bf16, zero-padded K)
__global__ void k_transpose_pad(const float* __restrict__ src, bf16_t* __restrict__ dst,
                                int K, int C, int Kpad) {
  int idx = blockIdx.x * 256 + threadIdx.x;
  if (idx >= C * Kpad) return;
  int c = idx / Kpad, kp = idx - c * Kpad;
  float v = (kp < K) ? src[(size_t)kp * C + c] : 0.0f;
  dst[idx] = (bf16_t)v;
}

// ---------------- stage 1: h[:, br*256+c] = relu(x_slice @ Wbr + bbr)   (bf16 out)
// 256 thr, BM=64, BN=256, BK=32; 4 waves each 64x64
__global__ __launch_bounds__(256, 2)
void k_branch_mlp(const float* __restrict__ x,
                  const bf16_t* __restrict__ W1T, const bf16_t* __restrict__ W2T,
                  const bf16_t* __restrict__ W3T,
                  const float* __restrict__ b1, const float* __restrict__ b2,
                  const float* __restrict__ b3,
                  bf16_t* __restrict__ h) {
  __shared__ __align__(16) bf16_t As[64 * 48];
  __shared__ __align__(16) bf16_t Bs[256 * 48];

  const int tid = threadIdx.x;
  const int lane = tid & 63, w = tid >> 6;
  const int ln = lane & 15, g = lane >> 4;
  const int row0 = blockIdx.x * 64;
  const int br = blockIdx.y;

  int Klim, Kpad, Foff;
  const bf16_t* BT; const float* bias;
  if (br == 0)      { Klim = 2000; Kpad = 2048; Foff = 0;    BT = W1T; bias = b1; }
  else if (br == 1) { Klim = 2000; Kpad = 2048; Foff = 2000; BT = W2T; bias = b2; }
  else              { Klim = 1000; Kpad = 1024; Foff = 4000; BT = W3T; bias = b3; }

  const int ar = tid >> 2, akq = tid & 3;  // A row 0..63, 8-f32 quarter
  const float* aptr = x + (size_t)(row0 + ar) * XC + Foff;
  const bf16_t* bptr = BT + (size_t)tid * Kpad;

  f32x4 zz = {0.f, 0.f, 0.f, 0.f};
  f32x4 acc[4][4];
#pragma unroll
  for (int m = 0; m < 4; ++m)
#pragma unroll
    for (int n = 0; n < 4; ++n) acc[m][n] = zz;

  float areg[8];
  bf16x8 breg[4];
  auto fetch = [&](int k0) {
    int kk = k0 + akq * 8;
    if (kk + 8 <= Klim) {
      float4 v0 = *(const float4*)(aptr + kk);
      float4 v1 = *(const float4*)(aptr + kk + 4);
      areg[0]=v0.x; areg[1]=v0.y; areg[2]=v0.z; areg[3]=v0.w;
      areg[4]=v1.x; areg[5]=v1.y; areg[6]=v1.z; areg[7]=v1.w;
    } else {
#pragma unroll
      for (int j = 0; j < 8; ++j) areg[j] = (kk + j < Klim) ? aptr[kk + j] : 0.0f;
    }
#pragma unroll
    for (int q = 0; q < 4; ++q) breg[q] = *(const bf16x8*)(bptr + k0 + q * 8);
  };

  fetch(0);
  for (int k0 = 0; k0 < Kpad; k0 += 32) {
    __syncthreads();
    bf16x8 av;
#pragma unroll
    for (int j = 0; j < 8; ++j) av[j] = (bf16_t)areg[j];
    *(bf16x8*)&As[ar * 48 + akq * 8] = av;
#pragma unroll
    for (int q = 0; q < 4; ++q) *(bf16x8*)&Bs[tid * 48 + q * 8] = breg[q];
    __syncthreads();
    if (k0 + 32 < Kpad) fetch(k0 + 32);
    bf16x8 af[4], bfr[4];
#pragma unroll
    for (int m = 0; m < 4; ++m) af[m] = *(const bf16x8*)&As[(16 * m + ln) * 48 + 8 * g];
#pragma unroll
    for (int n = 0; n < 4; ++n) bfr[n] = *(const bf16x8*)&Bs[(64 * w + 16 * n + ln) * 48 + 8 * g];
#pragma unroll
    for (int m = 0; m < 4; ++m)
#pragma unroll
      for (int n = 0; n < 4; ++n)
        acc[m][n] = MFMA16(acc[m][n], af[m], bfr[n]);
  }

  // epilogue: bias + relu -> h (row-major bf16). D frag: col=ln, row=4g+i.
#pragma unroll
  for (int n = 0; n < 4; ++n) {
    int cl = 64 * w + 16 * n + ln;
    float bv = bias[cl];
    int hcol = br * 256 + cl;
#pragma unroll
    for (int m = 0; m < 4; ++m)
#pragma unroll
      for (int i = 0; i < 4; ++i) {
        int rr = row0 + 16 * m + 4 * g + i;
        float v = acc[m][n][i] + bv;
        h[(size_t)rr * HD + hcol] = (bf16_t)(v > 0.f ? v : 0.f);
      }
  }
}

// ---------------- stage 2: t1 = h @ gw1; writes t1T[c][row] (bf16, transposed)
__global__ __launch_bounds__(256, 2)
void k_t1(const bf16_t* __restrict__ h, const bf16_t* __restrict__ gw1T,
          bf16_t* __restrict__ t1T) {
  __shared__ __align__(16) bf16_t As[64 * 48];
  __shared__ __align__(16) bf16_t Bs[256 * 48];
  const int tid = threadIdx.x;
  const int lane = tid & 63, w = tid >> 6;
  const int ln = lane & 15, g = lane >> 4;
  const int row0 = blockIdx.x * 64;
  const int ar = tid >> 2, akq = tid & 3;
  const bf16_t* aptr = h + (size_t)(row0 + ar) * HD;
  const bf16_t* bptr = gw1T + (size_t)tid * HD;

  f32x4 zz = {0.f, 0.f, 0.f, 0.f};
  f32x4 acc[4][4];
#pragma unroll
  for (int m = 0; m < 4; ++m)
#pragma unroll
    for (int n = 0; n < 4; ++n) acc[m][n] = zz;

  bf16x8 areg; bf16x8 breg[4];
  auto fetch = [&](int k0) {
    areg = *(const bf16x8*)(aptr + k0 + akq * 8);
#pragma unroll
    for (int q = 0; q < 4; ++q) breg[q] = *(const bf16x8*)(bptr + k0 + q * 8);
  };
  fetch(0);
  for (int k0 = 0; k0 < HD; k0 += 32) {
    __syncthreads();
    *(bf16x8*)&As[ar * 48 + akq * 8] = areg;
#pragma unroll
    for (int q = 0; q < 4; ++q) *(bf16x8*)&Bs[tid * 48 + q * 8] = breg[q];
    __syncthreads();
    if (k0 + 32 < HD) fetch(k0 + 32);
    bf16x8 af[4], bfr[4];
#pragma unroll
    for (int m = 0; m < 4; ++m) af[m] = *(const bf16x8*)&As[(16 * m + ln) * 48 + 8 * g];
#pragma unroll
    for (int n = 0; n < 4; ++n) bfr[n] = *(const bf16x8*)&Bs[(64 * w + 16 * n + ln) * 48 + 8 * g];
#pragma unroll
    for (int m = 0; m < 4; ++m)
#pragma unroll
      for (int n = 0; n < 4; ++n)
        acc[m][n] = MFMA16(acc[m][n], af[m], bfr[n]);
  }

  // epilogue: t1T[c][row0+16m+4g+i], 4 consecutive rows -> packed 8B store
#pragma unroll
  for (int n = 0; n < 4; ++n) {
    int c = 64 * w + 16 * n + ln;
#pragma unroll
    for (int m = 0; m < 4; ++m) {
      bf16x4 p;
#pragma unroll
      for (int i = 0; i < 4; ++i) p[i] = (bf16_t)acc[m][n][i];
      *(bf16x4*)(t1T + (size_t)c * NN + row0 + 16 * m + 4 * g) = p;
    }
  }
}

// ---------------- stage 3: g1 = relu(adj@t1 + gb1); t2 = g1@gw2 (in-LDS); writes t2T
// 512 thr (8 waves), BM=64, BN=256, BK=32; double-buffered LDS, 2-deep reg prefetch,
// ONE barrier per K-step.
__global__ __launch_bounds__(512)
void k_gcn1(const float* __restrict__ adj, const bf16_t* __restrict__ t1T,
            const float* __restrict__ gb1, const bf16_t* __restrict__ gw2T,
            bf16_t* __restrict__ t2T) {
  __shared__ __align__(16) char smem[78336];
  bf16_t* A0  = (bf16_t*)smem;             // 6144
  bf16_t* A1  = (bf16_t*)(smem + 6144);    // 6144
  bf16_t* B0  = (bf16_t*)(smem + 12288);   // 24576
  bf16_t* B1  = (bf16_t*)(smem + 36864);   // 24576
  bf16_t* g1s = (bf16_t*)smem;             // [64][264] 33792 (union with A0/A1/B0, post-loop)
  bf16_t* w2s = (bf16_t*)(smem + 61440);   // [32][264] 16896 (separate, preloaded once)

  const int tid = threadIdx.x;
  const int lane = tid & 63, w = tid >> 6;      // w: 0..7
  const int ln = lane & 15, g = lane >> 4;
  const int row0 = blockIdx.x * 64;

  const int ar = tid >> 3, akq = tid & 7;       // A: row 0..63, 4-f32 chunk 0..7
  const int bc = tid >> 1, bh = tid & 1;        // B: col 0..255, 16-bf16 half
  const float*  aptr = adj + (size_t)(row0 + ar) * NN + akq * 4;
  const bf16_t* bptr = t1T + (size_t)bc * NN + bh * 16;

  // gw2T -> w2s (separate region, never clobbered)
  for (int i = tid; i < 32 * 256; i += 512) {
    int rr = i >> 8, s = i & 255;
    w2s[rr * 264 + s] = gw2T[i];
  }

  f32x4 zz = {0.f, 0.f, 0.f, 0.f};
  f32x4 acc[4][2];
#pragma unroll
  for (int m = 0; m < 4; ++m) { acc[m][0] = zz; acc[m][1] = zz; }

  float4 raa; bf16x8 rab0, rab1;   // reg set A
  float4 rba; bf16x8 rbb0, rbb1;   // reg set B

  auto fetchR = [&](int t, float4& a, bf16x8& b0, bf16x8& b1) {
    int k0 = t * 32;
    a  = *(const float4*)(aptr + k0);
    b0 = *(const bf16x8*)(bptr + k0);
    b1 = *(const bf16x8*)(bptr + k0 + 8);
  };
  auto stage = [&](const float4& a, const bf16x8& b0, const bf16x8& b1,
                   bf16_t* Ad, bf16_t* Bd) {
    bf16x4 av;
    av[0] = (bf16_t)a.x; av[1] = (bf16_t)a.y;
    av[2] = (bf16_t)a.z; av[3] = (bf16_t)a.w;
    *(bf16x4*)&Ad[ar * 48 + akq * 4] = av;
    *(bf16x8*)&Bd[bc * 48 + bh * 16] = b0;
    *(bf16x8*)&Bd[bc * 48 + bh * 16 + 8] = b1;
  };
  auto compute = [&](const bf16_t* Ac, const bf16_t* Bc) {
    bf16x8 af[4], bfr[2];
#pragma unroll
    for (int m = 0; m < 4; ++m) af[m] = *(const bf16x8*)&Ac[(16 * m + ln) * 48 + 8 * g];
#pragma unroll
    for (int n = 0; n < 2; ++n) bfr[n] = *(const bf16x8*)&Bc[(32 * w + 16 * n + ln) * 48 + 8 * g];
#pragma unroll
    for (int m = 0; m < 4; ++m)
#pragma unroll
      for (int n = 0; n < 2; ++n)
        acc[m][n] = MFMA16(acc[m][n], af[m], bfr[n]);
  };

  // prologue: buf0 <- tile0; ra <- tile1; rb <- tile2 (in flight)
  fetchR(0, raa, rab0, rab1);
  stage(raa, rab0, rab1, A0, B0);
  fetchR(1, raa, rab0, rab1);
  fetchR(2, rba, rbb0, rbb1);
  __syncthreads();

  const int NT = NN / 32;  // 512
  for (int t = 0; t < NT; t += 2) {
    // even iter t: buf0 holds tile t; ra = tile t+1; rb in flight tile t+2
    stage(raa, rab0, rab1, A1, B1);                 // tile t+1 -> buf1
    if (t + 3 < NT) fetchR(t + 3, raa, rab0, rab1); // issue tile t+3
    compute(A0, B0);
    __syncthreads();
    // odd iter t+1: buf1 holds tile t+1; rb = tile t+2; ra in flight tile t+3
    if (t + 2 < NT) stage(rba, rbb0, rbb1, A0, B0); // tile t+2 -> buf0
    if (t + 4 < NT) fetchR(t + 4, rba, rbb0, rbb1); // issue tile t+4
    compute(A1, B1);
    __syncthreads();
  }

  // epilogue: g1 = relu(acc+gb1) -> LDS (bf16), then t2 = g1 @ gw2 via MFMA, write t2T
#pragma unroll
  for (int n = 0; n < 2; ++n) {
    int cl = 32 * w + 16 * n + ln;
    float bv = gb1[cl];
#pragma unroll
    for (int m = 0; m < 4; ++m)
#pragma unroll
      for (int i = 0; i < 4; ++i) {
        float v = acc[m][n][i] + bv;
        g1s[(16 * m + 4 * g + i) * 264 + cl] = (bf16_t)(v > 0.f ? v : 0.f);
      }
  }
  __syncthreads();
  {
    int rw = w & 3, cn = w >> 2;   // 8 waves cover 4 row-groups x 2 col-frags
    f32x4 macc = zz;
#pragma unroll
    for (int ks = 0; ks < 8; ++ks) {
      bf16x8 ag = *(const bf16x8*)&g1s[(16 * rw + ln) * 264 + ks * 32 + 8 * g];
      bf16x8 bg = *(const bf16x8*)&w2s[(16 * cn + ln) * 264 + ks * 32 + 8 * g];
      macc = MFMA16(macc, ag, bg);
    }
    int c2 = 16 * cn + ln;
    bf16x4 p;
#pragma unroll
    for (int i = 0; i < 4; ++i) p[i] = (bf16_t)macc[i];
    *(bf16x4*)(t2T + (size_t)c2 * NN + row0 + 16 * rw + 4 * g) = p;
  }
}

// ---------------- stage 4: out = log_softmax(adj @ t2 + gb2)
// 256 thr, BM=32, per-wave split-K (4 x 4096), wave-private LDS, 2-deep reg prefetch
__global__ __launch_bounds__(256, 2)
void k_gcn2(const float* __restrict__ adj, const bf16_t* __restrict__ t2T,
            const float* __restrict__ gb2, float* __restrict__ out) {
  __shared__ __align__(16) char smem[49152];
  float* Lg = (float*)smem;  // [4][32][32] f32, union (post-loop)
  const int tid = threadIdx.x;
  const int lane = tid & 63, w = tid >> 6;
  const int ln = lane & 15, g = lane >> 4;
  const int row0 = blockIdx.x * 32;

  bf16_t* A0 = (bf16_t*)(smem + w * 12288);
  bf16_t* B0 = (bf16_t*)(smem + w * 12288 + 3072);
  bf16_t* A1 = (bf16_t*)(smem + w * 12288 + 6144);
  bf16_t* B1 = (bf16_t*)(smem + w * 12288 + 9216);

  const int ar = lane >> 1, akq = lane & 1;  // row/col 0..31, 16-elem half
  const float*  aptr = adj + (size_t)(row0 + ar) * NN + akq * 16;
  const bf16_t* bptr = t2T + (size_t)ar * NN + akq * 16;

  f32x4 zz = {0.f, 0.f, 0.f, 0.f};
  f32x4 macc[2][2];
#pragma unroll
  for (int m = 0; m < 2; ++m) { macc[m][0] = zz; macc[m][1] = zz; }

  const int kb0 = w * 4096;

  float4 ra0, ra1, ra2, ra3; bf16x8 rab0, rab1;  // reg set A
  float4 sa0, sa1, sa2, sa3; bf16x8 sbb0, sbb1;  // reg set B

  auto fetchR = [&](int s, float4& a0, float4& a1, float4& a2, float4& a3,
                    bf16x8& b0, bf16x8& b1) {
    int kb = kb0 + s * 32;
    a0 = *(const float4*)(aptr + kb);
    a1 = *(const float4*)(aptr + kb + 4);
    a2 = *(const float4*)(aptr + kb + 8);
    a3 = *(const float4*)(aptr + kb + 12);
    b0 = *(const bf16x8*)(bptr + kb);
    b1 = *(const bf16x8*)(bptr + kb + 8);
  };
  auto body = [&](const float4& a0, const float4& a1, const float4& a2, const float4& a3,
                  const bf16x8& b0, const bf16x8& b1, bf16_t* Ab, bf16_t* Bb) {
    bf16x8 av0, av1;
    av0[0]=(bf16_t)a0.x; av0[1]=(bf16_t)a0.y; av0[2]=(bf16_t)a0.z; av0[3]=(bf16_t)a0.w;
    av0[4]=(bf16_t)a1.x; av0[5]=(bf16_t)a1.y; av0[6]=(bf16_t)a1.z; av0[7]=(bf16_t)a1.w;
    av1[0]=(bf16_t)a2.x; av1[1]=(bf16_t)a2.y; av1[2]=(bf16_t)a2.z; av1[3]=(bf16_t)a2.w;
    av1[4]=(bf16_t)a3.x; av1[5]=(bf16_t)a3.y; av1[6]=(bf16_t)a3.z; av1[7]=(bf16_t)a3.w;
    *(bf16x8*)&Ab[ar * 48 + akq * 16] = av0;
    *(bf16x8*)&Ab[ar * 48 + akq * 16 + 8] = av1;
    *(bf16x8*)&Bb[ar * 48 + akq * 16] = b0;
    *(bf16x8*)&Bb[ar * 48 + akq * 16 + 8] = b1;
    bf16x8 af[2], bfr[2];
#pragma unroll
    for (int m = 0; m < 2; ++m) af[m] = *(const bf16x8*)&Ab[(16 * m + ln) * 48 + 8 * g];
#pragma unroll
    for (int n = 0; n < 2; ++n) bfr[n] = *(const bf16x8*)&Bb[(16 * n + ln) * 48 + 8 * g];
#pragma unroll
    for (int m = 0; m < 2; ++m)
#pragma unroll
      for (int n = 0; n < 2; ++n)
        macc[m][n] = MFMA16(macc[m][n], af[m], bfr[n]);
  };

  // prologue: ra <- tile0, sb <- tile1 (in flight)
  fetchR(0, ra0, ra1, ra2, ra3, rab0, rab1);
  fetchR(1, sa0, sa1, sa2, sa3, sbb0, sbb1);

  for (int s = 0; s < 128; s += 2) {
    // even: stage+compute tile s from reg set A; refill A with tile s+2
    {
      bf16x8 tb0 = rab0, tb1 = rab1;
      float4 t0 = ra0, t1 = ra1, t2 = ra2, t3 = ra3;
      if (s + 2 < 128) fetchR(s + 2, ra0, ra1, ra2, ra3, rab0, rab1);
      body(t0, t1, t2, t3, tb0, tb1, A0, B0);
    }
    // odd: tile s+1 from reg set B; refill B with tile s+3
    {
      bf16x8 tb0 = sbb0, tb1 = sbb1;
      float4 t0 = sa0, t1 = sa1, t2 = sa2, t3 = sa3;
      if (s + 3 < 128) fetchR(s + 3, sa0, sa1, sa2, sa3, sbb0, sbb1);
      body(t0, t1, t2, t3, tb0, tb1, A1, B1);
    }
  }

  __syncthreads();
#pragma unroll
  for (int m = 0; m < 2; ++m)
#pragma unroll
    for (int n = 0; n < 2; ++n)
#pragma unroll
      for (int i = 0; i < 4; ++i) {
        int rl = 16 * m + 4 * g + i;
        int cl = 16 * n + ln;
        Lg[(w * 32 + rl) * 32 + cl] = macc[m][n][i];
      }
  __syncthreads();

  // reduce 4 K-partials + bias, then log_softmax per row (8 threads/row)
  int rr = tid >> 3, cg = tid & 7;
  float l4[4];
#pragma unroll
  for (int j = 0; j < 4; ++j) {
    int c = cg * 4 + j;
    l4[j] = Lg[rr * 32 + c] + Lg[(32 + rr) * 32 + c] +
            Lg[(64 + rr) * 32 + c] + Lg[(96 + rr) * 32 + c] + gb2[c];
  }
  float mx = fmaxf(fmaxf(l4[0], l4[1]), fmaxf(l4[2], l4[3]));
  mx = fmaxf(mx, __shfl_xor(mx, 1));
  mx = fmaxf(mx, __shfl_xor(mx, 2));
  mx = fmaxf(mx, __shfl_xor(mx, 4));
  float se = 0.f;
#pragma unroll
  for (int j = 0; j < 4; ++j) se += expf(l4[j] - mx);
  se += __shfl_xor(se, 1);
  se += __shfl_xor(se, 2);
  se += __shfl_xor(se, 4);
  float lse = mx + logf(se);
  float4 o;
  o.x = l4[0] - lse; o.y = l4[1] - lse; o.z = l4[2] - lse; o.w = l4[3] - lse;
  *(float4*)&out[(size_t)(row0 + rr) * 32 + cg * 4] = o;
}

extern "C" void kernel_launch(void* const* d_in, const int* in_sizes, int n_in,
                              void* d_out, int out_size, void* d_ws, size_t ws_size,
                              hipStream_t stream) {
  const float* x   = (const float*)d_in[0];
  const float* adj = (const float*)d_in[1];
  const float* W1  = (const float*)d_in[2];
  const float* b1  = (const float*)d_in[3];
  const float* W2  = (const float*)d_in[4];
  const float* b2  = (const float*)d_in[5];
  const float* W3  = (const float*)d_in[6];
  const float* b3  = (const float*)d_in[7];
  const float* gw1 = (const float*)d_in[8];
  const float* gb1 = (const float*)d_in[9];
  const float* gw2 = (const float*)d_in[10];
  const float* gb2 = (const float*)d_in[11];
  float* out = (float*)d_out;

  char* ws = (char*)d_ws;
  size_t off = 0;
  auto alloc = [&](size_t bytes) { char* p = ws + off; off += (bytes + 255) & ~(size_t)255; return p; };
  bf16_t* W1T  = (bf16_t*)alloc((size_t)256 * 2048 * 2);
  bf16_t* W2T  = (bf16_t*)alloc((size_t)256 * 2048 * 2);
  bf16_t* W3T  = (bf16_t*)alloc((size_t)256 * 1024 * 2);
  bf16_t* gw1T = (bf16_t*)alloc((size_t)256 * 768 * 2);
  bf16_t* gw2T = (bf16_t*)alloc((size_t)32 * 256 * 2);
  bf16_t* h    = (bf16_t*)alloc((size_t)NN * HD * 2);
  bf16_t* t1T  = (bf16_t*)alloc((size_t)256 * NN * 2);
  bf16_t* t2T  = (bf16_t*)alloc((size_t)32 * NN * 2);
  if (ws_size < off) return;  // workspace too small: bail (bench will show absmax fail)

  k_transpose_pad<<<(256 * 2048 + 255) / 256, 256, 0, stream>>>(W1, W1T, 2000, 256, 2048);
  k_transpose_pad<<<(256 * 2048 + 255) / 256, 256, 0, stream>>>(W2, W2T, 2000, 256, 2048);
  k_transpose_pad<<<(256 * 1024 + 255) / 256, 256, 0, stream>>>(W3, W3T, 1000, 256, 1024);
  k_transpose_pad<<<(256 * 768  + 255) / 256, 256, 0, stream>>>(gw1, gw1T, 768, 256, 768);
  k_transpose_pad<<<(32 * 256   + 255) / 256, 256, 0, stream>>>(gw2, gw2T, 256, 32, 256);

  k_branch_mlp<<<dim3(256, 3), 256, 0, stream>>>(x, W1T, W2T, W3T, b1, b2, b3, h);
  k_t1<<<256, 256, 0, stream>>>(h, gw1T, t1T);
  k_gcn1<<<256, 512, 0, stream>>>(adj, t1T, gb1, gw2T, t2T);
  k_gcn2<<<512, 256, 0, stream>>>(adj, t2T, gb2, out);
}